// Round 4
// baseline (120.841 us; speedup 1.0000x reference)
//
#include <hip/hip_runtime.h>

// 3x3 conv, stride 1, pad 1, 4096x4096 fp32.
// R11: single-variable A/B vs R10 — NT stores -> regular cached stores.
// Rationale (R10 post-mortem): R7/R9/R10 (50/62/100% occupancy, 1.125-1.5x
// read amp) all total 112.4-112.8 us; conv saturates ~28 us at ~4.7 TB/s
// effective. NT stores force the 64 MiB output drain to HBM inside the conv
// window (the one non-BW-saturated window in the graph); cached stores land
// in L2/L3 (out fits in 256 MiB L3) and write back lazily, overlapping the
// next 256 MiB harness fill. Predicted: conv ~28 -> 18-22 us, total -> ~107.
// If total is unchanged, the combined-bytes roofline
// ((512 MB fills + 134 MB conv)/6.3 TB/s ~ 103 us) is binding -> ROOFLINE.

#define H 4096
#define W 4096
#define CPT 4                    // cols per thread
#define RPT 4                    // output rows per block
#define BLOCK 256
#define NROWS (RPT + 2)          // 6 input rows
#define NBX (W / (BLOCK * CPT))  // 4 col-blocks
#define NBY (H / RPT)            // 1024 row-stripes
#define XCDS 8
#define BANDY (NBY / XCDS)       // 128 stripes per XCD band

typedef float vfloat4 __attribute__((ext_vector_type(4)));

__global__ __launch_bounds__(BLOCK, 8) void conv3x3_stripe(
    const float* __restrict__ x, const float* __restrict__ w9,
    const float* __restrict__ bias, float* __restrict__ out) {
    // XCD-banded bijective remap: linear id round-robins across 8 XCDs, so
    // id = slot*8 + xcd gives each XCD a contiguous band of 128 stripes;
    // within a band, bx varies fastest so vertically adjacent stripes are
    // temporally close on the same XCD's L2.
    const int id = blockIdx.x;
    const int xcd = id & (XCDS - 1);
    const int slot = id >> 3;                 // 0..511
    const int bx = slot & (NBX - 1);          // 0..3
    const int byb = slot >> 2;                // 0..127
    const int by = xcd * BANDY + byb;         // 0..1023

    const int c = (bx * BLOCK + threadIdx.x) * CPT;
    const int rbase = by * RPT;
    const int lane = threadIdx.x & 63;
    const bool isL = (lane == 0);
    const bool isR = (lane == 63);

    // Issue all 6 vector row loads up front (max MLP).
    vfloat4 v[NROWS];
#pragma unroll
    for (int i = 0; i < NROWS; ++i) {
        const int rr = rbase - 1 + i;
        if (rr >= 0 && rr < H)
            v[i] = *(const vfloat4*)(x + (size_t)rr * W + c);
        else
            v[i] = (vfloat4)(0.f);
    }

    // Wave-edge halo patches: lane 0 needs col c-1, lane 63 needs col c+4;
    // all other lanes get halos from neighbor lanes via shuffles below.
    float edge[NROWS];
#pragma unroll
    for (int i = 0; i < NROWS; ++i) edge[i] = 0.f;
    if (isL) {
#pragma unroll
        for (int i = 0; i < NROWS; ++i) {
            const int rr = rbase - 1 + i;
            if (rr >= 0 && rr < H && c > 0)
                edge[i] = x[(size_t)rr * W + c - 1];
        }
    } else if (isR) {
#pragma unroll
        for (int i = 0; i < NROWS; ++i) {
            const int rr = rbase - 1 + i;
            if (rr >= 0 && rr < H && c + CPT < W)
                edge[i] = x[(size_t)rr * W + c + CPT];
        }
    }

    // Uniform loads -> SGPRs.
    float wv[9];
#pragma unroll
    for (int i = 0; i < 9; ++i) wv[i] = w9[i];
    const float b = bias[0];

    vfloat4 acc[RPT];
#pragma unroll
    for (int j = 0; j < RPT; ++j) acc[j] = (vfloat4)(b);

    // Row-streaming accumulation: input row i contributes to outputs
    // j = i-2..i (tap dr = i-j). Per-output order is rows j, j+1, j+2 —
    // identical to R9/R10, so numerics are unchanged.
#pragma unroll
    for (int i = 0; i < NROWS; ++i) {
        float lfv = __shfl_up(v[i].w, 1);
        float rtv = __shfl_down(v[i].x, 1);
        lfv = isL ? edge[i] : lfv;
        rtv = isR ? edge[i] : rtv;
#pragma unroll
        for (int dr = 0; dr < 3; ++dr) {
            const int j = i - dr;
            if (j >= 0 && j < RPT) {
                const float w0 = wv[dr * 3 + 0];
                const float w1 = wv[dr * 3 + 1];
                const float w2 = wv[dr * 3 + 2];
                acc[j].x = fmaf(w0, lfv,    fmaf(w1, v[i].x, fmaf(w2, v[i].y, acc[j].x)));
                acc[j].y = fmaf(w0, v[i].x, fmaf(w1, v[i].y, fmaf(w2, v[i].z, acc[j].y)));
                acc[j].z = fmaf(w0, v[i].y, fmaf(w1, v[i].z, fmaf(w2, v[i].w, acc[j].z)));
                acc[j].w = fmaf(w0, v[i].z, fmaf(w1, v[i].w, fmaf(w2, rtv,    acc[j].w)));
            }
        }
    }

    // R11: regular cached stores (NOT nontemporal) — land in L2/L3 and let
    // the HBM writeback overlap the next graph dispatch instead of draining
    // synchronously inside the conv window.
#pragma unroll
    for (int j = 0; j < RPT; ++j) {
        *(vfloat4*)(out + (size_t)(rbase + j) * W + c) = acc[j];
    }
}

extern "C" void kernel_launch(void* const* d_in, const int* in_sizes, int n_in,
                              void* d_out, int out_size, void* d_ws, size_t ws_size,
                              hipStream_t stream) {
    const float* x = (const float*)d_in[0];
    const float* w = (const float*)d_in[1];
    const float* bias = (const float*)d_in[2];
    float* out = (float*)d_out;

    dim3 block(BLOCK, 1, 1);
    dim3 grid(NBX * NBY, 1, 1);   // 4096 blocks, XCD-banded remap in-kernel
    conv3x3_stripe<<<grid, block, 0, stream>>>(x, w, bias, out);
}

// Round 5
// 111.444 us; speedup vs baseline: 1.0843x; 1.0843x over previous
//
#include <hip/hip_runtime.h>

// 3x3 conv, stride 1, pad 1, 4096x4096 fp32.
// R12: REVERT to the session-best R7 configuration (112.4 us harness-verified).
// Session conclusions baked into this choice:
//   - R8 (32-row stripes, 2 blk/CU): conv latency-bound at 20% occ -> 48.6 us. BAD.
//   - R9/R10: occupancy 60%/100% variants -> conv ~28 us, totals 117/112.8;
//     occupancy beyond ~50% buys nothing (conv overlaps harness fills on HBM;
//     combined-bytes floor ~107 us governs the total).
//   - R11 A/B: cached stores regress 8 us vs NT — NT streams the 64 MiB out
//     without polluting L2/L3 that the 2x268 MB harness fills sweep anyway.
// Structure: block = 256 threads covering a 1024-col x 16-row stripe, walked
// in 4 steps of 4 output rows. Register rotation for the 2 overlapping rows;
// NT stores; prefetch distance 2 (rows for step s+2 issued during step s).

#define H 4096
#define W 4096
#define CPT 4      // cols per thread
#define RPT 4      // rows per step
#define STEPS 4    // steps per block (stripe = 16 rows)
#define BLOCK 256

typedef float vfloat4 __attribute__((ext_vector_type(4)));

__device__ __forceinline__ void load_row(const float* __restrict__ x, int rr,
                                         int c, vfloat4& v, float& lf, float& rt) {
    if (rr >= 0 && rr < H) {
        const float* row = x + (size_t)rr * W + c;
        v = *(const vfloat4*)row;
        lf = (c > 0) ? row[-1] : 0.0f;
        rt = (c + CPT < W) ? row[CPT] : 0.0f;
    } else {
        v = (vfloat4)(0.f);
        lf = 0.f;
        rt = 0.f;
    }
}

__global__ __launch_bounds__(BLOCK, 4) void conv3x3_stripe(
    const float* __restrict__ x, const float* __restrict__ w9,
    const float* __restrict__ bias, float* __restrict__ out) {
    const int c = (blockIdx.x * BLOCK + threadIdx.x) * CPT;
    const int rbase = blockIdx.y * (STEPS * RPT);

    float wv[9];
#pragma unroll
    for (int i = 0; i < 9; ++i) wv[i] = w9[i];
    const float b = bias[0];

    // Current window: rows rbase-1 .. rbase+4.
    vfloat4 v[6];
    float lf[6], rt[6];
#pragma unroll
    for (int i = 0; i < 6; ++i) load_row(x, rbase - 1 + i, c, v[i], lf[i], rt[i]);

    // Prefetch stage 1: rows rbase+5 .. rbase+8 (for step 1).
    vfloat4 p[4];
    float plf[4], prt[4];
#pragma unroll
    for (int k = 0; k < 4; ++k) load_row(x, rbase + 5 + k, c, p[k], plf[k], prt[k]);

#pragma unroll
    for (int s = 0; s < STEPS; ++s) {
        const int r0 = rbase + s * RPT;

        // Prefetch stage 2: rows r0+9 .. r0+12 (for step s+2).
        vfloat4 q[4];
        float qlf[4], qrt[4];
        if (s < STEPS - 2) {
#pragma unroll
            for (int k = 0; k < 4; ++k)
                load_row(x, r0 + 9 + k, c, q[k], qlf[k], qrt[k]);
        }

        vfloat4 acc[RPT];
#pragma unroll
        for (int j = 0; j < RPT; ++j) acc[j] = (vfloat4)(b);

#pragma unroll
        for (int j = 0; j < RPT; ++j) {
#pragma unroll
            for (int dr = 0; dr < 3; ++dr) {
                const int i = j + dr;
                const float w0 = wv[dr * 3 + 0];
                const float w1 = wv[dr * 3 + 1];
                const float w2 = wv[dr * 3 + 2];
                acc[j].x = fmaf(w0, lf[i],  fmaf(w1, v[i].x, fmaf(w2, v[i].y, acc[j].x)));
                acc[j].y = fmaf(w0, v[i].x, fmaf(w1, v[i].y, fmaf(w2, v[i].z, acc[j].y)));
                acc[j].z = fmaf(w0, v[i].y, fmaf(w1, v[i].z, fmaf(w2, v[i].w, acc[j].z)));
                acc[j].w = fmaf(w0, v[i].z, fmaf(w1, v[i].w, fmaf(w2, rt[i],  acc[j].w)));
            }
        }

#pragma unroll
        for (int j = 0; j < RPT; ++j) {
            __builtin_nontemporal_store(acc[j],
                (vfloat4*)(out + (size_t)(r0 + j) * W + c));
        }

        // Rotate window and pipeline stages (full unroll -> pure renaming).
        if (s < STEPS - 1) {
            v[0] = v[4];  v[1] = v[5];
            lf[0] = lf[4]; lf[1] = lf[5];
            rt[0] = rt[4]; rt[1] = rt[5];
#pragma unroll
            for (int k = 0; k < 4; ++k) {
                v[2 + k] = p[k];
                lf[2 + k] = plf[k];
                rt[2 + k] = prt[k];
                p[k] = q[k];
                plf[k] = qlf[k];
                prt[k] = qrt[k];
            }
        }
    }
}

extern "C" void kernel_launch(void* const* d_in, const int* in_sizes, int n_in,
                              void* d_out, int out_size, void* d_ws, size_t ws_size,
                              hipStream_t stream) {
    const float* x = (const float*)d_in[0];
    const float* w = (const float*)d_in[1];
    const float* bias = (const float*)d_in[2];
    float* out = (float*)d_out;

    dim3 block(BLOCK, 1, 1);
    dim3 grid(W / (BLOCK * CPT), H / (STEPS * RPT), 1);
    conv3x3_stripe<<<grid, block, 0, stream>>>(x, w, bias, out);
}